// Round 2
// baseline (234.518 us; speedup 1.0000x reference)
//
#include <hip/hip_runtime.h>
#include <hip/hip_bf16.h>

// Block-sparse attention (dkernel-style): B=2, S=4096, H=16, D=128,
// BS=64 blocks, NB=64, LOCAL=8, GLOBAL=1. fp32 in/out, bf16 MFMA compute.

typedef __bf16 bf16_t;
typedef bf16_t bf16x8 __attribute__((ext_vector_type(8)));
typedef bf16_t bf16x4 __attribute__((ext_vector_type(4)));
typedef float f32x4 __attribute__((ext_vector_type(4)));

#define BSZ 64
#define DIM 128
#define NH 16
#define SEQ 4096
#define ROWSTRIDE (NH * DIM)  // 2048 floats between consecutive sequence rows

#define KB_LD 136   // 64 x 136 bf16  (pad 128->136: 272B rows, 2-way bank alias)
#define VT_LD 72    // 128 x 72 bf16  (pad 64->72: 144B rows, 2-way bank alias)
#define P_LD  72    // 16 x 72 bf16 per wave

__global__ __launch_bounds__(256) void sparse_attn_kernel(
    const float* __restrict__ q, const float* __restrict__ k,
    const float* __restrict__ v, float* __restrict__ out)
{
    __shared__ bf16_t Kb[BSZ][KB_LD];
    __shared__ bf16_t Vt[DIM][VT_LD];
    __shared__ bf16_t Pl[4][16][P_LD];

    const int bid = blockIdx.x;
    const int qi = bid & 63;
    const int h  = (bid >> 6) & 15;
    const int b  = bid >> 10;

    const int tid  = threadIdx.x;
    const int wave = tid >> 6;
    const int lane = tid & 63;
    const int lr = lane & 15;   // fragment row (A) / col (B,D) index
    const int lk = lane >> 4;   // k-group
    const int k0 = lk * 8;

    const float sm_scale = 0.08838834764831845f;  // 1/sqrt(128)

    const size_t bh_off = ((size_t)b * SEQ * NH + (size_t)h) * DIM;

    // ---- Q fragments in registers: wave owns q rows [qi*64+wave*16, +16) ----
    bf16x8 qf[4];
    {
        const float* qrow = q + bh_off + (size_t)(qi * 64 + wave * 16 + lr) * ROWSTRIDE;
        for (int kk = 0; kk < 4; ++kk) {
            const float4 a0 = *(const float4*)(qrow + 32 * kk + k0);
            const float4 a1 = *(const float4*)(qrow + 32 * kk + k0 + 4);
            bf16x8 f;
            f[0] = (bf16_t)a0.x; f[1] = (bf16_t)a0.y;
            f[2] = (bf16_t)a0.z; f[3] = (bf16_t)a0.w;
            f[4] = (bf16_t)a1.x; f[5] = (bf16_t)a1.y;
            f[6] = (bf16_t)a1.z; f[7] = (bf16_t)a1.w;
            qf[kk] = f;
        }
    }

    // ---- accumulators ----
    f32x4 oacc[8];
    for (int n = 0; n < 8; ++n) oacc[n] = (f32x4){0.f, 0.f, 0.f, 0.f};
    float mrun[4], lrun[4];
    for (int r = 0; r < 4; ++r) { mrun[r] = -3.0e38f; lrun[r] = 0.f; }

    const int nnz = (qi < 8) ? (qi + 1) : 9;

    for (int t = 0; t < nnz; ++t) {
        const int j = (qi < 8) ? t : ((t == 0) ? 0 : (qi - 8 + t));

        // ---- stage K (row-major bf16) and V (transposed bf16) ----
        {
            const float* kbase = k + bh_off + (size_t)(j * 64) * ROWSTRIDE;
            const float* vbase = v + bh_off + (size_t)(j * 64) * ROWSTRIDE;
            for (int f = tid; f < 2048; f += 256) {
                const int row = f >> 5;        // 0..63 (kv row)
                const int c4  = f & 31;        // float4 index within row
                const float4 kv4 = *(const float4*)(kbase + (size_t)row * ROWSTRIDE + c4 * 4);
                bf16x4 kq = {(bf16_t)kv4.x, (bf16_t)kv4.y, (bf16_t)kv4.z, (bf16_t)kv4.w};
                *(bf16x4*)&Kb[row][c4 * 4] = kq;
                const float4 vv4 = *(const float4*)(vbase + (size_t)row * ROWSTRIDE + c4 * 4);
                Vt[c4 * 4 + 0][row] = (bf16_t)vv4.x;
                Vt[c4 * 4 + 1][row] = (bf16_t)vv4.y;
                Vt[c4 * 4 + 2][row] = (bf16_t)vv4.z;
                Vt[c4 * 4 + 3][row] = (bf16_t)vv4.w;
            }
        }
        __syncthreads();

        // ---- S = Q * K^T for this wave's 16 rows (16x64) ----
        f32x4 sacc[4];
        for (int n = 0; n < 4; ++n) {
            f32x4 a = (f32x4){0.f, 0.f, 0.f, 0.f};
            for (int kk = 0; kk < 4; ++kk) {
                bf16x8 kf = *(const bf16x8*)&Kb[16 * n + lr][32 * kk + k0];
                a = __builtin_amdgcn_mfma_f32_16x16x32_bf16(qf[kk], kf, a, 0, 0, 0);
            }
            sacc[n] = a;
        }

        // ---- scale + causal mask (diagonal block only) + row max ----
        const bool diag = (j == qi);
        float vmax[4];
        for (int r = 0; r < 4; ++r) vmax[r] = -3.0e38f;
        for (int n = 0; n < 4; ++n) {
            for (int r = 0; r < 4; ++r) {
                float s = sacc[n][r] * sm_scale;
                if (diag) {
                    const int col  = 16 * n + lr;             // kv index in 64-block
                    const int rowq = wave * 16 + 4 * lk + r;  // q index in 64-block (FIX)
                    if (col > rowq) s = -3.0e38f;
                }
                sacc[n][r] = s;
                vmax[r] = fmaxf(vmax[r], s);
            }
        }
        for (int r = 0; r < 4; ++r) {
            float m = vmax[r];
            m = fmaxf(m, __shfl_xor(m, 1));
            m = fmaxf(m, __shfl_xor(m, 2));
            m = fmaxf(m, __shfl_xor(m, 4));
            m = fmaxf(m, __shfl_xor(m, 8));
            vmax[r] = m;
        }

        // ---- online softmax update ----
        float alpha[4], rowsum[4];
        for (int r = 0; r < 4; ++r) {
            const float mnew = fmaxf(mrun[r], vmax[r]);
            alpha[r]  = __expf(mrun[r] - mnew);
            mrun[r]   = mnew;
            rowsum[r] = 0.f;
        }
        for (int n = 0; n < 4; ++n) {
            for (int r = 0; r < 4; ++r) {
                const float p = __expf(sacc[n][r] - mrun[r]);
                rowsum[r] += p;
                Pl[wave][4 * lk + r][16 * n + lr] = (bf16_t)p;
            }
        }
        for (int r = 0; r < 4; ++r) {
            float s = rowsum[r];
            s += __shfl_xor(s, 1);
            s += __shfl_xor(s, 2);
            s += __shfl_xor(s, 4);
            s += __shfl_xor(s, 8);
            lrun[r] = lrun[r] * alpha[r] + s;
        }
        for (int n = 0; n < 8; ++n)
            for (int r = 0; r < 4; ++r)
                oacc[n][r] *= alpha[r];

        // ---- O += P * V  (A = P from wave-private LDS, B = Vt columns) ----
        for (int n = 0; n < 8; ++n) {
            f32x4 a = oacc[n];
            for (int kk = 0; kk < 2; ++kk) {
                bf16x8 pf = *(const bf16x8*)&Pl[wave][lr][32 * kk + k0];
                bf16x8 vf = *(const bf16x8*)&Vt[16 * n + lr][32 * kk + k0];
                a = __builtin_amdgcn_mfma_f32_16x16x32_bf16(pf, vf, a, 0, 0, 0);
            }
            oacc[n] = a;
        }
        __syncthreads();  // protect Kb/Vt before next stage
    }

    // ---- epilogue: normalize and store fp32 ----
    float* obase = out + bh_off + (size_t)(qi * 64 + wave * 16) * ROWSTRIDE;
    for (int r = 0; r < 4; ++r) {
        const float inv = 1.0f / lrun[r];
        float* orow = obase + (size_t)(4 * lk + r) * ROWSTRIDE;
        for (int n = 0; n < 8; ++n) {
            orow[16 * n + lr] = oacc[n][r] * inv;
        }
    }
}

extern "C" void kernel_launch(void* const* d_in, const int* in_sizes, int n_in,
                              void* d_out, int out_size, void* d_ws, size_t ws_size,
                              hipStream_t stream) {
    const float* q = (const float*)d_in[0];
    const float* k = (const float*)d_in[1];
    const float* v = (const float*)d_in[2];
    float* out = (float*)d_out;
    dim3 grid(2048);
    dim3 block(256);
    sparse_attn_kernel<<<grid, block, 0, stream>>>(q, k, v, out);
}

// Round 3
// 141.835 us; speedup vs baseline: 1.6535x; 1.6535x over previous
//
#include <hip/hip_runtime.h>
#include <hip/hip_bf16.h>

// Block-sparse attention: B=2, S=4096, H=16, D=128, BS=64, LOCAL=8, GLOBAL=1.
// fp32 in/out, bf16 MFMA compute, flash-style online softmax (exp2 domain).

typedef __bf16 bf16_t;
typedef bf16_t bf16x8 __attribute__((ext_vector_type(8)));
typedef bf16_t bf16x4 __attribute__((ext_vector_type(4)));
typedef float f32x4 __attribute__((ext_vector_type(4)));

#define BSZ 64
#define DIM 128
#define NH 16
#define SEQ 4096
#define ROWSTRIDE (NH * DIM)
#define KB_LD 136   // 272B rows: QK B-frag reads conflict-free (bank stride 4)

// Vt: linear [d=128][k=64] bf16 (128B rows), XOR-swizzled: fold d's low 3 bits
// (addr bits 9-11) into bank bits 4-6. Stores (lanes along d) and reads
// (lanes along d) both <=2-way.
__device__ __forceinline__ uint32_t vt_swz(uint32_t A) {
    return A ^ (((A >> 9) & 7u) << 4);
}

__global__ __launch_bounds__(256) void sparse_attn_kernel(
    const float* __restrict__ q, const float* __restrict__ k,
    const float* __restrict__ v, float* __restrict__ out)
{
    __shared__ __align__(16) bf16_t Kb[BSZ][KB_LD];
    __shared__ __align__(16) bf16_t Vt[DIM * BSZ];
    __shared__ __align__(16) bf16_t Pl[4][16][72];

    // XCD-aware swizzle: 2048 blocks, 8 XCDs -> contiguous 256-chunk per XCD.
    const int L  = ((blockIdx.x & 7) << 8) | (blockIdx.x >> 3);
    const int qi = L & 63;
    const int h  = (L >> 6) & 15;
    const int b  = L >> 10;

    const int tid  = threadIdx.x;
    const int wave = tid >> 6;
    const int lane = tid & 63;
    const int lr = lane & 15;
    const int lk = lane >> 4;
    const int k0 = lk * 8;

    const int sc4 = tid & 31;  // staging: float4 column 0..31
    const int sr  = tid >> 5;  // staging: row group 0..7

    const float scale2 = 0.12751649736230476f;  // (1/sqrt(128)) * log2(e)

    const size_t bh_off = ((size_t)b * SEQ * NH + (size_t)h) * DIM;
    const float* kbh = k + bh_off;
    const float* vbh = v + bh_off;

    // ---- Q fragments (wave owns q rows [qi*64+wave*16, +16)) ----
    bf16x8 qf[4];
    {
        const float* qrow = q + bh_off + (size_t)(qi * 64 + wave * 16 + lr) * ROWSTRIDE;
        #pragma unroll
        for (int kk = 0; kk < 4; ++kk) {
            const float4 a0 = *(const float4*)(qrow + 32 * kk + k0);
            const float4 a1 = *(const float4*)(qrow + 32 * kk + k0 + 4);
            bf16x8 f;
            f[0] = (bf16_t)a0.x; f[1] = (bf16_t)a0.y;
            f[2] = (bf16_t)a0.z; f[3] = (bf16_t)a0.w;
            f[4] = (bf16_t)a1.x; f[5] = (bf16_t)a1.y;
            f[6] = (bf16_t)a1.z; f[7] = (bf16_t)a1.w;
            qf[kk] = f;
        }
    }

    f32x4 oacc[8];
    #pragma unroll
    for (int n = 0; n < 8; ++n) oacc[n] = (f32x4){0.f, 0.f, 0.f, 0.f};
    float mrun[4], lrun[4];
    #pragma unroll
    for (int r = 0; r < 4; ++r) { mrun[r] = -3.0e38f; lrun[r] = 0.f; }

    const int nnz = (qi < 8) ? (qi + 1) : 9;

    // ---- register prefetch buffers (T14 async-stage split) ----
    float4 kreg[8];   // K row (8i+sr), cols 4*sc4..+3
    float4 vreg[8];   // V row 4*(sr+8*T)+i, cols 4*sc4..+3  (T=idx>>2, i=idx&3)

    #define LOAD_KV(jb)                                                           \
    {                                                                             \
        const float* kb_ = kbh + (size_t)((jb) * 64) * ROWSTRIDE + 4 * sc4;       \
        const float* vb_ = vbh + (size_t)((jb) * 64) * ROWSTRIDE + 4 * sc4;       \
        _Pragma("unroll")                                                         \
        for (int i = 0; i < 8; ++i)                                               \
            kreg[i] = *(const float4*)(kb_ + (size_t)(8 * i + sr) * ROWSTRIDE);   \
        _Pragma("unroll")                                                         \
        for (int T = 0; T < 2; ++T)                                               \
            _Pragma("unroll")                                                     \
            for (int i = 0; i < 4; ++i)                                           \
                vreg[T * 4 + i] = *(const float4*)(vb_ +                          \
                    (size_t)(4 * (sr + 8 * T) + i) * ROWSTRIDE);                  \
    }

    LOAD_KV(0);  // j_of(0) == 0 for every qi

    for (int t = 0; t < nnz; ++t) {
        const int j = (qi < 8) ? t : ((t == 0) ? 0 : (qi - 8 + t));

        // ---- regs -> LDS (waits on the prefetch loads) ----
        #pragma unroll
        for (int i = 0; i < 8; ++i) {
            const float4 t4 = kreg[i];
            bf16x4 c = {(bf16_t)t4.x, (bf16_t)t4.y, (bf16_t)t4.z, (bf16_t)t4.w};
            *(bf16x4*)&Kb[8 * i + sr][4 * sc4] = c;
        }
        #pragma unroll
        for (int T = 0; T < 2; ++T) {
            #pragma unroll
            for (int j2 = 0; j2 < 4; ++j2) {
                const int d = 4 * sc4 + j2;
                bf16x4 c = {(bf16_t)((const float*)&vreg[T * 4 + 0])[j2],
                            (bf16_t)((const float*)&vreg[T * 4 + 1])[j2],
                            (bf16_t)((const float*)&vreg[T * 4 + 2])[j2],
                            (bf16_t)((const float*)&vreg[T * 4 + 3])[j2]};
                const uint32_t A = vt_swz((uint32_t)(d * 128 + 8 * (sr + 8 * T)));
                *(bf16x4*)((char*)Vt + A) = c;
            }
        }
        __syncthreads();

        // ---- issue next block's loads; they complete under the compute below --
        if (t + 1 < nnz) {
            const int jn = (qi < 8) ? (t + 1) : (qi - 8 + t + 1);
            LOAD_KV(jn);
        }

        // ---- S = Q * K^T (16x64 per wave) ----
        f32x4 sacc[4];
        __builtin_amdgcn_s_setprio(1);
        #pragma unroll
        for (int n = 0; n < 4; ++n) {
            f32x4 a = (f32x4){0.f, 0.f, 0.f, 0.f};
            #pragma unroll
            for (int kk = 0; kk < 4; ++kk) {
                bf16x8 kf = *(const bf16x8*)&Kb[16 * n + lr][32 * kk + k0];
                a = __builtin_amdgcn_mfma_f32_16x16x32_bf16(qf[kk], kf, a, 0, 0, 0);
            }
            sacc[n] = a;
        }
        __builtin_amdgcn_s_setprio(0);

        // ---- scale (exp2 domain) + causal mask + row max ----
        const bool diag = (j == qi);
        float vmax[4];
        #pragma unroll
        for (int r = 0; r < 4; ++r) vmax[r] = -3.0e38f;
        #pragma unroll
        for (int n = 0; n < 4; ++n) {
            #pragma unroll
            for (int r = 0; r < 4; ++r) {
                float s = sacc[n][r] * scale2;
                if (diag) {
                    const int col  = 16 * n + lr;
                    const int rowq = wave * 16 + 4 * lk + r;
                    if (col > rowq) s = -1.0e30f;
                }
                sacc[n][r] = s;
                vmax[r] = fmaxf(vmax[r], s);
            }
        }
        #pragma unroll
        for (int r = 0; r < 4; ++r) {
            float m = vmax[r];
            m = fmaxf(m, __shfl_xor(m, 1));
            m = fmaxf(m, __shfl_xor(m, 2));
            m = fmaxf(m, __shfl_xor(m, 4));
            m = fmaxf(m, __shfl_xor(m, 8));
            vmax[r] = m;
        }

        // ---- online softmax (defer-max, THR=8 in log2 units) ----
        bool defer = true;
        #pragma unroll
        for (int r = 0; r < 4; ++r) defer &= (vmax[r] - mrun[r] <= 8.0f);
        if (!__all(defer)) {
            #pragma unroll
            for (int r = 0; r < 4; ++r) {
                const float mnew = fmaxf(mrun[r], vmax[r]);
                const float alpha = exp2f(mrun[r] - mnew);
                mrun[r] = mnew;
                lrun[r] *= alpha;
                #pragma unroll
                for (int n = 0; n < 8; ++n) oacc[n][r] *= alpha;
            }
        }
        float rowsum[4];
        #pragma unroll
        for (int r = 0; r < 4; ++r) rowsum[r] = 0.f;
        #pragma unroll
        for (int n = 0; n < 4; ++n) {
            #pragma unroll
            for (int r = 0; r < 4; ++r) {
                const float p = exp2f(sacc[n][r] - mrun[r]);
                rowsum[r] += p;
                Pl[wave][4 * lk + r][16 * n + lr] = (bf16_t)p;
            }
        }
        #pragma unroll
        for (int r = 0; r < 4; ++r) {
            float s = rowsum[r];
            s += __shfl_xor(s, 1);
            s += __shfl_xor(s, 2);
            s += __shfl_xor(s, 4);
            s += __shfl_xor(s, 8);
            lrun[r] += s;
        }

        // ---- O += P * V ----
        __builtin_amdgcn_s_setprio(1);
        #pragma unroll
        for (int n = 0; n < 8; ++n) {
            f32x4 a = oacc[n];
            #pragma unroll
            for (int kk = 0; kk < 2; ++kk) {
                bf16x8 pf = *(const bf16x8*)&Pl[wave][lr][32 * kk + k0];
                const uint32_t A = vt_swz((uint32_t)((16 * n + lr) * 128 + 64 * kk + 16 * lk));
                bf16x8 vf = *(const bf16x8*)((const char*)Vt + A);
                a = __builtin_amdgcn_mfma_f32_16x16x32_bf16(pf, vf, a, 0, 0, 0);
            }
            oacc[n] = a;
        }
        __builtin_amdgcn_s_setprio(0);
        __syncthreads();
    }

    // ---- epilogue ----
    float* obase = out + bh_off + (size_t)(qi * 64 + wave * 16) * ROWSTRIDE;
    #pragma unroll
    for (int r = 0; r < 4; ++r) {
        const float inv = 1.0f / lrun[r];
        float* orow = obase + (size_t)(4 * lk + r) * ROWSTRIDE;
        #pragma unroll
        for (int n = 0; n < 8; ++n) {
            orow[16 * n + lr] = oacc[n][r] * inv;
        }
    }
}

extern "C" void kernel_launch(void* const* d_in, const int* in_sizes, int n_in,
                              void* d_out, int out_size, void* d_ws, size_t ws_size,
                              hipStream_t stream) {
    const float* q = (const float*)d_in[0];
    const float* k = (const float*)d_in[1];
    const float* v = (const float*)d_in[2];
    float* out = (float*)d_out;
    sparse_attn_kernel<<<dim3(2048), dim3(256), 0, stream>>>(q, k, v, out);
}